// Round 6
// baseline (190.202 us; speedup 1.0000x reference)
//
#include <hip/hip_runtime.h>

// B=4, H=8, Nt=Nc=2048, D=512, E=64, scale = 1/64 folded into Wq at cast.
#define B_   4
#define H_   8
#define NSEQ 2048
#define D_   512
#define E_   64

typedef __bf16 bf16x8 __attribute__((ext_vector_type(8)));
typedef float  f32x4  __attribute__((ext_vector_type(4)));
typedef float  f32x16 __attribute__((ext_vector_type(16)));

__device__ __forceinline__ unsigned short f2b(float f) {
    __bf16 h = (__bf16)f;                     // RNE
    return __builtin_bit_cast(unsigned short, h);
}
__device__ __forceinline__ unsigned pk2(float a, float b) {
    return (unsigned)f2b(a) | ((unsigned)f2b(b) << 16);
}
__device__ __forceinline__ bf16x8 ld_frag(const unsigned short* p) {
    return *reinterpret_cast<const bf16x8*>(p);
}
// async global->LDS, 16B per lane: LDS dest = wave-uniform base + lane*16.
__device__ __forceinline__ void async_copy16(const void* g, const unsigned short* l) {
    __builtin_amdgcn_global_load_lds(
        (const __attribute__((address_space(1))) unsigned int*)g,
        (__attribute__((address_space(3))) unsigned int*)l, 16, 0, 0);
}

// ---------------------------------------------------------------------------
// Interleaved-2 LDS tile layout (bank-conflict-free b128 frag reads).
// Real rows are 128 B; two consecutive rows share one 256 B lds-row.
// 16B block (r, s) [s = 0..7] lives at block index:
//     lr = r>>1;  B' = (((r&1)<<3) | s) ^ (lr & 15)
// With only 8 slots per 128B row, ANY swizzle leaves 8 lanes per bank-group
// (8-way, 2x the b128 floor). 16 slots per 256B lds-row + 4-bit XOR gives
// exactly 4 lanes per bank-group = the b128 floor, for every frag-read
// pattern in this file (verified per-pattern by counting (e,q,t) solutions).
// Staging stays global_load_lds-compatible: linear LDS dest, per-lane
// REMAPPED global source (the bijection inverse), loop-invariant offsets.
// ---------------------------------------------------------------------------
__device__ __forceinline__ int lds_blk(int r, int s) {
    int lr = r >> 1;
    return lr * 128 + (((((r & 1) << 3) | s) ^ (lr & 15)) << 3);  // ushort idx
}
// staging inverse: instruction covers 8 real rows from r0 (r0%8==0);
// lane l supplies (row, slot):
//   lr = r0/2 + (l>>4); B = (l&15) ^ (lr&15); row = (lr<<1)|(B>>3); slot = B&7
#define STAGE_SRC(r0, l, row, slot)                                            \
    {   int lr_ = ((r0) >> 1) + ((l) >> 4);                                    \
        int B_x = ((l) & 15) ^ (lr_ & 15);                                     \
        row = (lr_ << 1) | (B_x >> 3);  slot = B_x & 7; }

// ---------------------------------------------------------------------------
// Cast + transpose W: [H][D][E] fp32 -> [he][d] bf16 (y=0..2); Wout (y=3).
// Wq (y=2) pre-scaled by 1/64 (exact exponent shift).
// ---------------------------------------------------------------------------
__global__ __launch_bounds__(256)
void cast_w_kernel(const float* __restrict__ Wk, const float* __restrict__ Wv,
                   const float* __restrict__ Wq, const float* __restrict__ Wo,
                   unsigned short* __restrict__ okt, unsigned short* __restrict__ ovt,
                   unsigned short* __restrict__ oqt, unsigned short* __restrict__ oo) {
    int idx = blockIdx.x * 256 + threadIdx.x;   // < 262144
    int y = blockIdx.y;
    if (y == 3) { oo[idx] = f2b(Wo[idx]); return; }
    const float* src = y == 0 ? Wk : (y == 1 ? Wv : Wq);
    unsigned short* dst = y == 0 ? okt : (y == 1 ? ovt : oqt);
    float scl = (y == 2) ? 0.015625f : 1.0f;
    int hh = idx >> 15, rem = idx & 32767, d = rem >> 6, e = rem & 63;
    dst[hh * 32768 + e * 512 + d] = f2b(src[idx] * scl);   // [(h*64+e)][d]
}

// ---------------------------------------------------------------------------
// X cast: fp32 [8192][512] -> bf16 [8192][512], y selects q/k/v.
// ---------------------------------------------------------------------------
__global__ __launch_bounds__(256)
void xcast_kernel(const float* __restrict__ q, const float* __restrict__ k,
                  const float* __restrict__ v,
                  unsigned short* __restrict__ qx, unsigned short* __restrict__ kx,
                  unsigned short* __restrict__ vx) {
    const int y = blockIdx.y;
    const float* src = y == 0 ? q : (y == 1 ? k : v);
    unsigned short* dst = y == 0 ? qx : (y == 1 ? kx : vx);
    #pragma unroll
    for (int i = 0; i < 4; ++i) {
        int e = blockIdx.x * 4096 + i * 1024 + threadIdx.x * 4;
        float4 f = *reinterpret_cast<const float4*>(src + e);
        *reinterpret_cast<ushort4*>(dst + e) =
            make_ushort4(f2b(f.x), f2b(f.y), f2b(f.z), f2b(f.w));
    }
}

// ---------------------------------------------------------------------------
// Projection NT-GEMM (pure bf16): C[m][he] = sum_d X[m][d]*Wt[he][d].
// 8192x512x512, which: 0=Q 1=K 2=V. 128x64 tile, BK=64.
// Interleaved-2 LDS layout (conflict-free frag reads).
// ---------------------------------------------------------------------------
__global__ __launch_bounds__(256, 3)
void proj_gemm(const unsigned short* __restrict__ qx,
               const unsigned short* __restrict__ kx,
               const unsigned short* __restrict__ vx,
               const unsigned short* __restrict__ wqt,
               const unsigned short* __restrict__ wkt,
               const unsigned short* __restrict__ wvt,
               unsigned short* __restrict__ qb, unsigned short* __restrict__ kb,
               unsigned short* __restrict__ vtb) {
    const int m0  = blockIdx.x * 128;
    const int no0 = blockIdx.y * 64;
    const int which = blockIdx.z;
    const int tid = threadIdx.x;
    const int wave = tid >> 6, lane = tid & 63;
    const int quad = lane >> 4, l16 = lane & 15;

    const unsigned short* X = which == 0 ? qx : (which == 1 ? kx : vx);
    const unsigned short* W = which == 0 ? wqt : (which == 1 ? wkt : wvt);

    __shared__ unsigned short Ab[2][8192];   // 2 x 16 KB (128 rows x 128 B)
    __shared__ unsigned short Bb[2][4096];   // 2 x  8 KB ( 64 rows x 128 B)

    const unsigned short* Xp = X + (size_t)m0 * D_;
    const unsigned short* Wp = W + (size_t)no0 * D_;

    // per-lane staging source (loop-invariant): A 4 slabs, B 2 slabs per wave
    int rowA[4], slA[4], rowB[2], slB[2];
    #pragma unroll
    for (int i = 0; i < 4; ++i) STAGE_SRC(wave * 32 + i * 8, lane, rowA[i], slA[i])
    #pragma unroll
    for (int i = 0; i < 2; ++i) STAGE_SRC(wave * 16 + i * 8, lane, rowB[i], slB[i])

    #define PROJ_STAGE(kt, buf)                                                \
        {   _Pragma("unroll")                                                  \
            for (int i = 0; i < 4; ++i)                                        \
                async_copy16(Xp + (size_t)rowA[i] * D_ + (kt) * 64 + slA[i] * 8, \
                             &Ab[buf][(wave * 32 + i * 8) * 64]);              \
            _Pragma("unroll")                                                  \
            for (int i = 0; i < 2; ++i)                                        \
                async_copy16(Wp + (size_t)rowB[i] * D_ + (kt) * 64 + slB[i] * 8, \
                             &Bb[buf][(wave * 16 + i * 8) * 64]);              \
        }

    PROJ_STAGE(0, 0)
    __syncthreads();                          // vmcnt drain: tile 0 resident

    const f32x4 z = {0.f, 0.f, 0.f, 0.f};
    f32x4 acc[2][4];
    #pragma unroll
    for (int i = 0; i < 2; ++i)
        #pragma unroll
        for (int j = 0; j < 4; ++j) acc[i][j] = z;

    for (int kt = 0; kt < 8; ++kt) {
        const int cur = kt & 1;
        if (kt + 1 < 8) PROJ_STAGE(kt + 1, 1 - cur)   // in flight over compute
        #pragma unroll
        for (int kk = 0; kk < 2; ++kk) {
            const int s = kk * 4 + quad;      // 16B slot of this k-octet
            bf16x8 bfr[4];
            #pragma unroll
            for (int nt = 0; nt < 4; ++nt)
                bfr[nt] = ld_frag(&Bb[cur][lds_blk(nt * 16 + l16, s)]);
            #pragma unroll
            for (int mt = 0; mt < 2; ++mt) {
                bf16x8 af = ld_frag(&Ab[cur][lds_blk(wave * 32 + mt * 16 + l16, s)]);
                #pragma unroll
                for (int nt = 0; nt < 4; ++nt)
                    acc[mt][nt] = __builtin_amdgcn_mfma_f32_16x16x32_bf16(
                        af, bfr[nt], acc[mt][nt], 0, 0, 0);
            }
        }
        __syncthreads();                      // drains vmcnt (tile kt+1) + lgkm
    }

    // epilogue: overlay staging on Ab (32 KB contiguous)
    if (which != 2) {
        unsigned short (*Os)[72] = reinterpret_cast<unsigned short(*)[72]>(&Ab[0][0]);
        #pragma unroll
        for (int mt = 0; mt < 2; ++mt)
            #pragma unroll
            for (int nt = 0; nt < 4; ++nt)
                #pragma unroll
                for (int r = 0; r < 4; ++r)
                    Os[wave * 32 + mt * 16 + quad * 4 + r][nt * 16 + l16] =
                        f2b(acc[mt][nt][r]);
        __syncthreads();
        unsigned short* Y = (which == 0 ? qb : kb);
        #pragma unroll
        for (int i = 0; i < 4; ++i) {           // 128 rows x 8 uint4
            int idx = tid + i * 256;
            int row = idx >> 3, seg = idx & 7;
            *reinterpret_cast<uint4*>(Y + (size_t)(m0 + row) * D_ + no0 + seg * 8) =
                *reinterpret_cast<const uint4*>(&Os[row][seg * 8]);
        }
    } else {
        unsigned short (*Ot)[136] = reinterpret_cast<unsigned short(*)[136]>(&Ab[0][0]);
        #pragma unroll
        for (int mt = 0; mt < 2; ++mt)
            #pragma unroll
            for (int nt = 0; nt < 4; ++nt) {
                ushort4 o = make_ushort4(f2b(acc[mt][nt][0]), f2b(acc[mt][nt][1]),
                                         f2b(acc[mt][nt][2]), f2b(acc[mt][nt][3]));
                *reinterpret_cast<ushort4*>(
                    &Ot[nt * 16 + l16][wave * 32 + mt * 16 + quad * 4]) = o;
            }
        __syncthreads();
        const int b = m0 >> 11, nloc = m0 & 2047;
        #pragma unroll
        for (int i = 0; i < 4; ++i) {           // 64 he-rows x 16 uint4
            int idx = tid + i * 256;
            int lhe = idx >> 4, seg = idx & 15;
            int ghe = no0 + lhe;                 // h = ghe>>6, e = ghe&63
            *reinterpret_cast<uint4*>(
                vtb + ((size_t)(b * H_ + (ghe >> 6)) * E_ + (ghe & 63)) * NSEQ +
                nloc + seg * 8) =
                *reinterpret_cast<const uint4*>(&Ot[lhe][seg * 8]);
        }
    }
    #undef PROJ_STAGE
}

// ---------------------------------------------------------------------------
// Flash attention, 32x32x16 MFMA, in-register P (permlane exchange), same
// structure as round 5 but with the interleaved-2 conflict-free LDS layout.
//   wk = wave>>1 (key half), wq = wave&1 (q half); 4 waves, 64-row Q tiles.
//   S = mfma(K,Q); P = exp(S) in regs; permlane32_swap -> PV B-operand;
//   O-partials combined across wk through LDS in the epilogue. m=0 softmax.
// LDS 32 KB -> 4+ blocks/CU, grid 1024, no tail.
// ---------------------------------------------------------------------------
__global__ __launch_bounds__(256, 3)
void attn_kernel(const unsigned short* __restrict__ qbp,
                 const unsigned short* __restrict__ kbp,
                 const unsigned short* __restrict__ vtbp,
                 unsigned short* __restrict__ aob) {
    const int L = blockIdx.x;
    const int bh = L & 31, qt = L >> 5;      // L%8 pattern -> XCD K/V affinity
    const int b = bh >> 3, h = bh & 7;
    const int n0 = qt * 64;
    const int tid = threadIdx.x;
    const int wave = tid >> 6, lane = tid & 63;
    const int wk = wave >> 1, wq = wave & 1;
    const int l32 = lane & 31, hi = lane >> 5;

    __shared__ unsigned short Ks[2][4096];   // 16 KiB (dbuf K, 64 rows)
    __shared__ unsigned short Vs[2][4096];   // 16 KiB (dbuf V^T, 64 e-rows)

    const unsigned short* kbase = kbp + (size_t)(b * NSEQ) * D_ + h * 64;
    const unsigned short* vbase = vtbp + (size_t)(b * H_ + h) * E_ * NSEQ;

    // per-lane staging source (loop-invariant): 2 slabs of 8 rows per wave
    int rowS[2], slS[2];
    #pragma unroll
    for (int i = 0; i < 2; ++i) STAGE_SRC(wave * 16 + i * 8, lane, rowS[i], slS[i])

    // Q B-frags (32x32x16 B layout: lane&31 = q col, k-octet = hi):
    bf16x8 qf[4];
    #pragma unroll
    for (int ks = 0; ks < 4; ++ks)
        qf[ks] = ld_frag(qbp + (size_t)(b * NSEQ + n0 + wq * 32 + l32) * D_ +
                         h * 64 + ks * 16 + hi * 8);

    #define ATTN_STAGE(j, buf)                                                 \
        {   _Pragma("unroll")                                                  \
            for (int i = 0; i < 2; ++i) {                                      \
                async_copy16(                                                  \
                    kbase + (size_t)((j) * 64 + rowS[i]) * D_ + slS[i] * 8,    \
                    &Ks[buf][wave * 1024 + i * 512]);                          \
                async_copy16(                                                  \
                    vbase + (size_t)rowS[i] * NSEQ + (j) * 64 + slS[i] * 8,    \
                    &Vs[buf][wave * 1024 + i * 512]);                          \
            } }

    ATTN_STAGE(0, 0)
    __syncthreads();                            // vmcnt drain: tile 0 resident

    f32x16 oacc[2] = {};                        // O^T[eb*32 + crow][q], own keys
    float lacc = 0.f;

    for (int j = 0; j < NSEQ / 64; ++j) {
        const int cur = j & 1;
        if (j + 1 < NSEQ / 64) ATTN_STAGE(j + 1, 1 - cur)   // in flight over compute

        const unsigned short* Kc = Ks[cur];
        const unsigned short* Vc = Vs[cur];

        // S-block = mfma(K, Q): A = K[key = wk*32 + l32][k-octet ks*2 + hi]
        f32x16 sacc = {};
        #pragma unroll
        for (int ks = 0; ks < 4; ++ks) {
            bf16x8 kf = ld_frag(&Kc[lds_blk(wk * 32 + l32, ks * 2 + hi)]);
            sacc = __builtin_amdgcn_mfma_f32_32x32x16_bf16(kf, qf[ks], sacc, 0, 0, 0);
        }

        // exp (m=0); lane holds P for 16 keys: k_local = (r&3)+8*(r>>2)+4*hi
        float p[16];
        #pragma unroll
        for (int r = 0; r < 16; ++r) p[r] = __expf(sacc[r]);
        lacc += ((p[0] + p[1]) + (p[2] + p[3])) + ((p[4] + p[5]) + (p[6] + p[7])) +
                (((p[8] + p[9]) + (p[10] + p[11])) + ((p[12] + p[13]) + (p[14] + p[15])));

        // Build PV B-frags in-register: pack bf16 pairs, then swap lane-halves.
        #pragma unroll
        for (int s = 0; s < 2; ++s) {
            unsigned x0 = pk2(p[s * 8 + 0], p[s * 8 + 1]);
            unsigned x1 = pk2(p[s * 8 + 2], p[s * 8 + 3]);
            unsigned y0 = pk2(p[s * 8 + 4], p[s * 8 + 5]);
            unsigned y1 = pk2(p[s * 8 + 6], p[s * 8 + 7]);
            asm volatile("v_permlane32_swap_b32 %0, %1" : "+v"(x0), "+v"(y0));
            asm volatile("v_permlane32_swap_b32 %0, %1" : "+v"(x1), "+v"(y1));
            uint4 u = make_uint4(x0, x1, y0, y1);
            bf16x8 pb = __builtin_bit_cast(bf16x8, u);
            // O^T += V^T·P : A = V^T[e = eb*32 + l32][k-octet wk*4 + s*2 + hi]
            #pragma unroll
            for (int eb = 0; eb < 2; ++eb) {
                bf16x8 vf = ld_frag(&Vc[lds_blk(eb * 32 + l32, wk * 4 + s * 2 + hi)]);
                oacc[eb] = __builtin_amdgcn_mfma_f32_32x32x16_bf16(
                    vf, pb, oacc[eb], 0, 0, 0);
            }
        }

        __syncthreads();   // drains vmcnt (tile j+1 committed) + lgkm; flips buffers
    }

    // ---- epilogue: combine wk pairs through LDS (Ks/Vs dead), normalize ----
    lacc += __shfl_xor(lacc, 32);              // wave partial l(q), q = l32
    float* Of = reinterpret_cast<float*>(&Ks[0][0]);   // [wq][32 q][64 e] = 16 KB
    float* Lf = reinterpret_cast<float*>(&Vs[0][0]);   // [wq][32 q]
    if (wk == 0) {
        #pragma unroll
        for (int eb = 0; eb < 2; ++eb)
            #pragma unroll
            for (int rg = 0; rg < 4; ++rg) {
                f32x4 v = {oacc[eb][rg * 4 + 0], oacc[eb][rg * 4 + 1],
                           oacc[eb][rg * 4 + 2], oacc[eb][rg * 4 + 3]};
                *reinterpret_cast<f32x4*>(
                    &Of[(wq * 32 + l32) * 64 + eb * 32 + rg * 8 + hi * 4]) = v;
            }
        if (hi == 0) Lf[wq * 32 + l32] = lacc;
    }
    __syncthreads();
    if (wk == 1) {
        const float li = 1.0f / (lacc + Lf[wq * 32 + l32]);
        unsigned short* op =
            aob + (size_t)(b * NSEQ + n0 + wq * 32 + l32) * D_ + h * 64;
        #pragma unroll
        for (int eb = 0; eb < 2; ++eb)
            #pragma unroll
            for (int rg = 0; rg < 4; ++rg) {
                const f32x4 o = *reinterpret_cast<const f32x4*>(
                    &Of[(wq * 32 + l32) * 64 + eb * 32 + rg * 8 + hi * 4]);
                ushort4 st = make_ushort4(f2b((oacc[eb][rg * 4 + 0] + o.x) * li),
                                          f2b((oacc[eb][rg * 4 + 1] + o.y) * li),
                                          f2b((oacc[eb][rg * 4 + 2] + o.z) * li),
                                          f2b((oacc[eb][rg * 4 + 3] + o.w) * li));
                *reinterpret_cast<ushort4*>(op + eb * 32 + rg * 8 + hi * 4) = st;
            }
    }
    #undef ATTN_STAGE
}

// ---------------------------------------------------------------------------
// Output NT-GEMM: Out[m][o] = sum_d aob[m][d] * Wout[o][d]. 8192x512x512.
// Interleaved-2 LDS layout; fp32 direct-store epilogue.
// ---------------------------------------------------------------------------
__global__ __launch_bounds__(256, 3)
void out_gemm(const unsigned short* __restrict__ A,
              const unsigned short* __restrict__ Wo,
              float* __restrict__ Out) {
    const int m0  = blockIdx.x * 128;
    const int no0 = blockIdx.y * 64;
    const int tid = threadIdx.x;
    const int wave = tid >> 6, lane = tid & 63;
    const int quad = lane >> 4, l16 = lane & 15;

    __shared__ unsigned short Ab[2][8192];
    __shared__ unsigned short Bb[2][4096];

    const unsigned short* Ap = A + (size_t)m0 * D_;
    const unsigned short* Bp = Wo + (size_t)no0 * D_;

    int rowA[4], slA[4], rowB[2], slB[2];
    #pragma unroll
    for (int i = 0; i < 4; ++i) STAGE_SRC(wave * 32 + i * 8, lane, rowA[i], slA[i])
    #pragma unroll
    for (int i = 0; i < 2; ++i) STAGE_SRC(wave * 16 + i * 8, lane, rowB[i], slB[i])

    #define OUT_STAGE(kt, buf)                                                 \
        {   _Pragma("unroll")                                                  \
            for (int i = 0; i < 4; ++i)                                        \
                async_copy16(Ap + (size_t)rowA[i] * D_ + (kt) * 64 + slA[i] * 8, \
                             &Ab[buf][(wave * 32 + i * 8) * 64]);              \
            _Pragma("unroll")                                                  \
            for (int i = 0; i < 2; ++i)                                        \
                async_copy16(Bp + (size_t)rowB[i] * D_ + (kt) * 64 + slB[i] * 8, \
                             &Bb[buf][(wave * 16 + i * 8) * 64]);              \
        }

    OUT_STAGE(0, 0)
    __syncthreads();

    const f32x4 z = {0.f, 0.f, 0.f, 0.f};
    f32x4 acc[2][4];
    #pragma unroll
    for (int i = 0; i < 2; ++i)
        #pragma unroll
        for (int j = 0; j < 4; ++j) acc[i][j] = z;

    for (int kt = 0; kt < 8; ++kt) {
        const int cur = kt & 1;
        if (kt + 1 < 8) OUT_STAGE(kt + 1, 1 - cur)
        #pragma unroll
        for (int kk = 0; kk < 2; ++kk) {
            const int s = kk * 4 + quad;
            bf16x8 bfr[4];
            #pragma unroll
            for (int nt = 0; nt < 4; ++nt)
                bfr[nt] = ld_frag(&Bb[cur][lds_blk(nt * 16 + l16, s)]);
            #pragma unroll
            for (int mt = 0; mt < 2; ++mt) {
                bf16x8 af = ld_frag(&Ab[cur][lds_blk(wave * 32 + mt * 16 + l16, s)]);
                #pragma unroll
                for (int nt = 0; nt < 4; ++nt)
                    acc[mt][nt] = __builtin_amdgcn_mfma_f32_16x16x32_bf16(
                        af, bfr[nt], acc[mt][nt], 0, 0, 0);
            }
        }
        __syncthreads();
    }
    #pragma unroll
    for (int mt = 0; mt < 2; ++mt)
        #pragma unroll
        for (int nt = 0; nt < 4; ++nt)
            #pragma unroll
            for (int r = 0; r < 4; ++r)
                Out[(size_t)(m0 + wave * 32 + mt * 16 + quad * 4 + r) * D_ +
                    no0 + nt * 16 + l16] = acc[mt][nt][r];
    #undef OUT_STAGE
}

// ---------------------------------------------------------------------------
extern "C" void kernel_launch(void* const* d_in, const int* in_sizes, int n_in,
                              void* d_out, int out_size, void* d_ws, size_t ws_size,
                              hipStream_t stream) {
    const float* keys   = (const float*)d_in[0];
    const float* values = (const float*)d_in[1];
    const float* query  = (const float*)d_in[2];
    const float* Wk     = (const float*)d_in[3];
    const float* Wv     = (const float*)d_in[4];
    const float* Wq     = (const float*)d_in[5];
    const float* Wout   = (const float*)d_in[6];
    float* out = (float*)d_out;

    unsigned short* ws16 = (unsigned short*)d_ws;
    const size_t XN = (size_t)B_ * NSEQ * D_;      // 4,194,304
    const size_t WN = (size_t)H_ * D_ * E_;        // 262,144
    unsigned short* wkt = ws16;                    // [he][d]
    unsigned short* wvt = wkt + WN;
    unsigned short* wqt = wvt + WN;                // pre-scaled by 1/64
    unsigned short* wob = wqt + WN;
    unsigned short* qb  = wob + WN;                // [8192][512], col=h*64+e
    unsigned short* kb  = qb + XN;                 // [8192][512]
    unsigned short* vtb = kb + XN;                 // [b][h][e][n]
    unsigned short* aob = vtb + XN;                // [8192][512] head-concat
    unsigned short* qx  = aob + XN;                // bf16 query  [8192][512]
    unsigned short* kx  = qx + XN;                 // bf16 keys   [8192][512]
    unsigned short* vx  = aob;                     // bf16 values ALIASES aob:
                                                   // vx dead after proj; aob
                                                   // written only by attn (later)

    cast_w_kernel<<<dim3(1024, 4), 256, 0, stream>>>(Wk, Wv, Wq, Wout,
                                                     wkt, wvt, wqt, wob);

    xcast_kernel<<<dim3(1024, 3), 256, 0, stream>>>(query, keys, values,
                                                    qx, kx, vx);

    proj_gemm<<<dim3(64, 8, 3), 256, 0, stream>>>(
        qx, kx, vx, wqt, wkt, wvt, qb, kb, vtb);

    attn_kernel<<<dim3(1024), 256, 0, stream>>>(qb, kb, vtb, aob);

    out_gemm<<<dim3(64, 8), 256, 0, stream>>>(aob, wob, out);
}